// Round 11
// baseline (15.951 us; speedup 1.0000x reference)
//
#include <hip/hip_runtime.h>
#include <math.h>

#define NC   16
#define NCH  8                  // channels per thread (2 threads per position)
#define HWSZ (128 * 128)
#define NB   16
#define TOT  (NB * NC * HWSZ)   // 4,194,304 elements per output tensor

// Branchless erf, Abramowitz-Stegun 7.1.26, |err| <= 1.5e-7.
__device__ __forceinline__ float fast_erf(float v) {
    const float ax = fabsf(v);
    const float t  = __fdividef(1.0f, fmaf(0.3275911f, ax, 1.0f));
    float p = fmaf(1.061405429f, t, -1.453152027f);
    p = fmaf(p, t,  1.421413741f);
    p = fmaf(p, t, -0.284496736f);
    p = fmaf(p, t,  0.254829592f);
    p *= t;
    const float e = __expf(-v * v);
    return copysignf(fmaf(-p, e, 1.0f), v);
}

__global__ __launch_bounds__(256, 8) void moe_router_kernel(
    const float* __restrict__ x, const float* __restrict__ noise,
    const float* __restrict__ gp, const float* __restrict__ wnp,
    float* __restrict__ out)
{
    const int tid = blockIdx.x * blockDim.x + threadIdx.x;
    const int sp  = tid >> 1;           // spatial position (2 threads share one)
    const int cg  = tid & 1;            // channel group: 0 -> ch 0..7, 1 -> 8..15
    const int b   = sp >> 14;           // / HWSZ
    const int hw  = sp & (HWSZ - 1);
    const size_t base = (size_t)b * (NC * HWSZ) + hw + (size_t)(cg * NCH) * HWSZ;

    // Per-channel state in registers (fully unrolled, compile-time indices).
    float wg[NCH], wn[NCH], hl[NCH];
    float m1 = -INFINITY, m2 = -INFINITY;
    int   amax = 0;                     // absolute channel index

    // Pass 1: PLAIN loads (inputs stay L2/L3-resident across replays).
    // Lane pairs share sp -> two contiguous 128B segments per wave access.
    #pragma unroll
    for (int c = 0; c < NCH; ++c) {
        const float xv = x[base + (size_t)c * HWSZ];
        const float nv = noise[base + (size_t)c * HWSZ];
        const int   ac = cg * NCH + c;
        const float wgv = xv * gp[ac];
        const float z   = xv * wnp[ac];
        const float spv = fmaxf(z, 0.0f) + __logf(1.0f + __expf(-fabsf(z)));
        const float h   = __builtin_fmaf(nv, spv, wgv);
        wg[c] = wgv;
        wn[c] = spv;
        hl[c] = h;
        amax = (h > m1) ? ac : amax;         // strict > : first occurrence
        m2   = fmaxf(m2, fminf(m1, h));
        m1   = fmaxf(m1, h);
    }

    // Local softmax partial sum (relative to local max m1).
    float ssum = 0.0f;
    #pragma unroll
    for (int c = 0; c < NCH; ++c)
        ssum += __expf(hl[c] - m1);

    // Cross-thread combine with the partner lane (same wave, lane ^ 1).
    const float o_m1   = __shfl_xor(m1, 1);
    const float o_m2   = __shfl_xor(m2, 1);
    const int   o_amax = __shfl_xor(amax, 1);
    const float o_sum  = __shfl_xor(ssum, 1);

    // Order as (half0, half1) so ties pick the lower channel group.
    const float m1_0 = (cg == 0) ? m1   : o_m1;
    const float m1_1 = (cg == 0) ? o_m1 : m1;
    const float m2_0 = (cg == 0) ? m2   : o_m2;
    const float m2_1 = (cg == 0) ? o_m2 : m2;
    const int   am_0 = (cg == 0) ? amax : o_amax;
    const int   am_1 = (cg == 0) ? o_amax : amax;
    const float ss_0 = (cg == 0) ? ssum : o_sum;
    const float ss_1 = (cg == 0) ? o_sum : ssum;

    const float gm1  = fmaxf(m1_0, m1_1);
    const float gm2  = fmaxf(fminf(m1_0, m1_1), fmaxf(m2_0, m2_1));
    const int   gam  = (m1_0 >= m1_1) ? am_0 : am_1;   // first-occurrence tie-break
    const float gsum = __builtin_fmaf(ss_0, __expf(m1_0 - gm1),
                                      ss_1 * __expf(m1_1 - gm1));
    const float ginv = __fdividef(1.0f, gsum);

    // Pass 2: NT stores (one-shot output stream bypasses L2, keeps inputs hot).
    #pragma unroll
    for (int c = 0; c < NCH; ++c) {
        const int   ac  = cg * NCH + c;
        const bool  top = (ac == gam);
        const float mex = top ? gm2 : gm1;
        const float ll  = fast_erf(__fdividef(wg[c] - mex, wn[c]));
        __builtin_nontemporal_store(top ? ginv : 0.0f,
                                    out + base + (size_t)c * HWSZ);
        __builtin_nontemporal_store(ll, out + TOT + base + (size_t)c * HWSZ);
    }
}

extern "C" void kernel_launch(void* const* d_in, const int* in_sizes, int n_in,
                              void* d_out, int out_size, void* d_ws, size_t ws_size,
                              hipStream_t stream) {
    const float* x     = (const float*)d_in[0];
    const float* noise = (const float*)d_in[1];
    const float* gp    = (const float*)d_in[2];
    const float* wnp   = (const float*)d_in[3];
    float* out = (float*)d_out;

    const int threads = NB * HWSZ * 2;    // 524288 (2 threads per position)
    const int block   = 256;
    const int grid    = threads / block;  // 2048 blocks -> 32 waves/CU
    moe_router_kernel<<<grid, block, 0, stream>>>(x, noise, gp, wnp, out);
}

// Round 12
// 15.240 us; speedup vs baseline: 1.0467x; 1.0467x over previous
//
#include <hip/hip_runtime.h>
#include <math.h>

#define NC   16
#define HWSZ (128 * 128)
#define NB   16
#define TOT  (NB * NC * HWSZ)   // 4,194,304 elements per output tensor

// Branchless erf, Abramowitz-Stegun 7.1.26, |err| <= 1.5e-7.
__device__ __forceinline__ float fast_erf(float v) {
    const float ax = fabsf(v);
    const float t  = __fdividef(1.0f, fmaf(0.3275911f, ax, 1.0f));
    float p = fmaf(1.061405429f, t, -1.453152027f);
    p = fmaf(p, t,  1.421413741f);
    p = fmaf(p, t, -0.284496736f);
    p = fmaf(p, t,  0.254829592f);
    p *= t;
    const float e = __expf(-v * v);
    return copysignf(fmaf(-p, e, 1.0f), v);
}

// Best-measured configuration (R7): 1 position/thread, 16 waves/CU,
// plain cached loads (inputs L2/L3-resident), NT stores (one-shot output
// stream bypasses cache without evicting inputs). 15.2 us = 4.4 TB/s
// effective on 67 MB mandatory traffic (~70% of mixed-stream ceiling).
__global__ __launch_bounds__(256) void moe_router_kernel(
    const float* __restrict__ x, const float* __restrict__ noise,
    const float* __restrict__ gp, const float* __restrict__ wnp,
    float* __restrict__ out)
{
    const int t  = blockIdx.x * blockDim.x + threadIdx.x;  // one spatial elem
    const int b  = t >> 14;             // / HWSZ
    const int hw = t & (HWSZ - 1);
    const size_t base = (size_t)b * (NC * HWSZ) + hw;

    // Per-channel state in registers (fully unrolled, compile-time indices).
    float wg[NC], wn[NC], hl[NC];
    float m1 = -INFINITY, m2 = -INFINITY;
    int   amax = 0;

    // Pass 1: PLAIN loads -> inputs allocate in L2/L3 and stay resident
    // across graph replays. Coalesced: 64 lanes x 4B contiguous per stream.
    #pragma unroll
    for (int c = 0; c < NC; ++c) {
        const float xv = x[base + (size_t)c * HWSZ];
        const float nv = noise[base + (size_t)c * HWSZ];
        const float wgv = xv * gp[c];
        const float z   = xv * wnp[c];
        const float spv = fmaxf(z, 0.0f) + __logf(1.0f + __expf(-fabsf(z)));
        const float h   = __builtin_fmaf(nv, spv, wgv);
        wg[c] = wgv;
        wn[c] = spv;
        hl[c] = h;
        amax = (h > m1) ? c : amax;          // strict > : first-occurrence argmax
        m2   = fmaxf(m2, fminf(m1, h));      // branchless top-2
        m1   = fmaxf(m1, h);
    }

    // Pass 2: softmax denominator (m1 is the final max, no rescale needed).
    float ssum = 0.0f;
    #pragma unroll
    for (int c = 0; c < NC; ++c)
        ssum += __expf(hl[c] - m1);
    const float ginv = __fdividef(1.0f, ssum);

    // Pass 3: NT stores -> the 33.5 MB one-shot output stream does not
    // evict the inputs from L2/L3 (it is never re-read).
    #pragma unroll
    for (int c = 0; c < NC; ++c) {
        const bool  top = (c == amax);
        const float mex = top ? m2 : m1;
        const float ll  = fast_erf(__fdividef(wg[c] - mex, wn[c]));
        __builtin_nontemporal_store(top ? ginv : 0.0f, out + base + (size_t)c * HWSZ);
        __builtin_nontemporal_store(ll, out + TOT + base + (size_t)c * HWSZ);
    }
}

extern "C" void kernel_launch(void* const* d_in, const int* in_sizes, int n_in,
                              void* d_out, int out_size, void* d_ws, size_t ws_size,
                              hipStream_t stream) {
    const float* x     = (const float*)d_in[0];
    const float* noise = (const float*)d_in[1];
    const float* gp    = (const float*)d_in[2];
    const float* wnp   = (const float*)d_in[3];
    float* out = (float*)d_out;

    const int threads = NB * HWSZ;        // 262144 spatial positions
    const int block   = 256;
    const int grid    = threads / block;  // 1024 blocks, 16 waves/CU
    moe_router_kernel<<<grid, block, 0, stream>>>(x, noise, gp, wnp, out);
}